// Round 1
// baseline (750.762 us; speedup 1.0000x reference)
//
#include <hip/hip_runtime.h>
#include <hip/hip_bf16.h>

#define NN 50000
#define EE 800000

typedef __bf16 bf16x8_t __attribute__((ext_vector_type(8)));
typedef float f32x4_t __attribute__((ext_vector_type(4)));

__device__ __forceinline__ float silu_f(float v) {
    return v / (1.0f + __expf(-v));
}

// ---------------- prep: x -> bf16, weights -> transposed bf16 [n][k] ----------------
__global__ void prep_kernel(const float* __restrict__ x,
                            const float* __restrict__ We1,
                            const float* __restrict__ We2,
                            const float* __restrict__ Wn1,
                            const float* __restrict__ Wn2,
                            __bf16* __restrict__ xb,
                            __bf16* __restrict__ We1T,
                            __bf16* __restrict__ We2T,
                            __bf16* __restrict__ Wn1T,
                            __bf16* __restrict__ Wn2T) {
    int tid = blockIdx.x * blockDim.x + threadIdx.x;
    int np = gridDim.x * blockDim.x;
    const int NX = NN * 128 / 4;
    for (int i = tid; i < NX; i += np) {
        float4 v = ((const float4*)x)[i];
        __bf16* o = xb + (size_t)i * 4;
        o[0] = (__bf16)v.x; o[1] = (__bf16)v.y; o[2] = (__bf16)v.z; o[3] = (__bf16)v.w;
    }
    for (int i = tid; i < 256 * 128; i += np) {
        int k = i >> 7, n = i & 127;
        We1T[n * 256 + k] = (__bf16)We1[i];
    }
    for (int i = tid; i < 128 * 128; i += np) {
        int k = i >> 7, n = i & 127;
        We2T[n * 128 + k] = (__bf16)We2[i];
    }
    for (int i = tid; i < 256 * 128; i += np) {
        int k = i >> 7, n = i & 127;
        Wn1T[n * 256 + k] = (__bf16)Wn1[i];
    }
    for (int i = tid; i < 128 * 128; i += np) {
        int k = i >> 7, n = i & 127;
        Wn2T[n * 128 + k] = (__bf16)Wn2[i];
    }
}

// ---------------- edge kernel: fused gather + 2-layer MLP + gate + scatter ----------------
// block = 256 threads (4 waves), tile = 64 edges x 128 out cols, K1=256(+rank-1 epilogue), K2=128
__global__ __launch_bounds__(256, 2)
void edge_kernel(const __bf16* __restrict__ xb,
                 const float* __restrict__ pos,
                 const int* __restrict__ eidx,
                 const float* __restrict__ eattr,
                 const float* __restrict__ s,
                 const __bf16* __restrict__ We1T,
                 const float* __restrict__ We1,   // f32, for rows 256/257 (r2, edge_attr)
                 const float* __restrict__ be1,
                 const __bf16* __restrict__ We2T,
                 const float* __restrict__ be2,
                 const float* __restrict__ Wc,
                 const float* __restrict__ bc,
                 float* __restrict__ msum,
                 float* __restrict__ deg,
                 float* __restrict__ coord) {
    __shared__ __align__(16) char Abuf_raw[64 * 264 * 2];   // A-tile bf16 (stride 264); later m f32 (stride 132)
    __shared__ __align__(16) __bf16 Wt[128 * 56];           // B tile [n][k], stride 56
    __shared__ __align__(16) __bf16 A2[64 * 136];           // layer-1 output, stride 136
    __shared__ float s_r2[64], s_ea[64], s_sg[64], s_diff[64 * 3], s_wc[128];
    __shared__ int s_dst[64];

    __bf16* Abf = (__bf16*)Abuf_raw;
    float* Mf = (float*)Abuf_raw;

    const int t = threadIdx.x;
    const int e0 = blockIdx.x * 64;
    const int w = t >> 6;          // wave id 0..3 -> edge rows [16w,16w+16)
    const int lane = t & 63;
    const int m_ = lane & 15;
    const int q = lane >> 4;

    // per-edge scalars
    if (t < 64) {
        int e = e0 + t;
        int si = eidx[e];
        int di = eidx[EE + e];
        float dx = pos[di * 3 + 0] - pos[si * 3 + 0];
        float dy = pos[di * 3 + 1] - pos[si * 3 + 1];
        float dz = pos[di * 3 + 2] - pos[si * 3 + 2];
        s_diff[t * 3 + 0] = dx; s_diff[t * 3 + 1] = dy; s_diff[t * 3 + 2] = dz;
        s_r2[t] = dx * dx + dy * dy + dz * dz;
        s_ea[t] = eattr[e];
        s_sg[t] = s[si];
        s_dst[t] = di;
    } else if (t < 192) {
        s_wc[t - 64] = Wc[t - 64];
    }

    // stage A: cols 0..127 = x[dst], 128..255 = x[src]  (bf16, 16B chunks)
    for (int i = 0; i < 8; ++i) {
        int id = t + 256 * i;          // 0..2047 = 64 edges * 32 chunks
        int el = id >> 5;
        int ch = id & 31;
        int e = e0 + el;
        int node = (ch < 16) ? eidx[EE + e] : eidx[e];
        int c16 = ch & 15;
        uint4 v = *(const uint4*)(xb + (long)node * 128 + c16 * 8);
        *(uint4*)(Abf + el * 264 + ((ch < 16) ? 0 : 128) + c16 * 8) = v;
    }
    __syncthreads();

    f32x4_t acc[8];
#pragma unroll
    for (int ct = 0; ct < 8; ++ct) acc[ct] = (f32x4_t){0.f, 0.f, 0.f, 0.f};

    // ---- layer 1: [64,256] @ [256,128] ----
    for (int ks = 0; ks < 8; ++ks) {
#pragma unroll
        for (int i = 0; i < 2; ++i) {
            int c = t + 256 * i;               // 512 chunks of 8 elems = 128n x 32k
            int n = c >> 2, ko = (c & 3) * 8;
            uint4 v = *(const uint4*)(We1T + n * 256 + ks * 32 + ko);
            *(uint4*)(Wt + n * 56 + ko) = v;
        }
        __syncthreads();
        bf16x8_t a = *(const bf16x8_t*)(Abf + (w * 16 + m_) * 264 + ks * 32 + q * 8);
#pragma unroll
        for (int ct = 0; ct < 8; ++ct) {
            bf16x8_t b = *(const bf16x8_t*)(Wt + (ct * 16 + m_) * 56 + q * 8);
            acc[ct] = __builtin_amdgcn_mfma_f32_16x16x32_bf16(a, b, acc[ct], 0, 0, 0);
        }
        __syncthreads();
    }

    // epilogue 1: + b + r2*W[256] + ea*W[257], SiLU -> A2 (bf16)
#pragma unroll
    for (int ct = 0; ct < 8; ++ct) {
        int c = ct * 16 + m_;
        float w256 = We1[256 * 128 + c];
        float w257 = We1[257 * 128 + c];
        float b1 = be1[c];
#pragma unroll
        for (int r = 0; r < 4; ++r) {
            int el = w * 16 + q * 4 + r;
            float v = acc[ct][r] + b1 + s_r2[el] * w256 + s_ea[el] * w257;
            A2[el * 136 + c] = (__bf16)silu_f(v);
        }
    }
    __syncthreads();

#pragma unroll
    for (int ct = 0; ct < 8; ++ct) acc[ct] = (f32x4_t){0.f, 0.f, 0.f, 0.f};

    // ---- layer 2: [64,128] @ [128,128] ----
    for (int ks = 0; ks < 4; ++ks) {
#pragma unroll
        for (int i = 0; i < 2; ++i) {
            int c = t + 256 * i;
            int n = c >> 2, ko = (c & 3) * 8;
            uint4 v = *(const uint4*)(We2T + n * 128 + ks * 32 + ko);
            *(uint4*)(Wt + n * 56 + ko) = v;
        }
        __syncthreads();
        bf16x8_t a = *(const bf16x8_t*)(A2 + (w * 16 + m_) * 136 + ks * 32 + q * 8);
#pragma unroll
        for (int ct = 0; ct < 8; ++ct) {
            bf16x8_t b = *(const bf16x8_t*)(Wt + (ct * 16 + m_) * 56 + q * 8);
            acc[ct] = __builtin_amdgcn_mfma_f32_16x16x32_bf16(a, b, acc[ct], 0, 0, 0);
        }
        __syncthreads();
    }

    // epilogue 2: + b, SiLU, * s[src] -> Mf f32 (stride 132, aliases A-tile)
#pragma unroll
    for (int ct = 0; ct < 8; ++ct) {
        int c = ct * 16 + m_;
        float b2 = be2[c];
#pragma unroll
        for (int r = 0; r < 4; ++r) {
            int el = w * 16 + q * 4 + r;
            float v = acc[ct][r] + b2;
            Mf[el * 132 + c] = silu_f(v) * s_sg[el];
        }
    }
    __syncthreads();

    // scatter m into m_sum
    for (int i = 0; i < 32; ++i) {
        int id = t + 256 * i;          // 8192 = 64 x 128
        int el = id >> 7, c = id & 127;
        atomicAdd(&msum[(long)s_dst[el] * 128 + c], Mf[el * 132 + c]);
    }
    // gamma + coord + deg (one thread per edge)
    if (t < 64) {
        float g = bc[0];
        for (int k = 0; k < 128; ++k) g += Mf[t * 132 + k] * s_wc[k];
        int d = s_dst[t];
        atomicAdd(&deg[d], 1.0f);
        atomicAdd(&coord[d * 3 + 0], g * s_diff[t * 3 + 0]);
        atomicAdd(&coord[d * 3 + 1], g * s_diff[t * 3 + 1]);
        atomicAdd(&coord[d * 3 + 2], g * s_diff[t * 3 + 2]);
    }
}

// ---------------- node kernel: normalize agg + 2-layer node MLP ----------------
__global__ __launch_bounds__(256, 2)
void node_kernel(const __bf16* __restrict__ xb,
                 const float* __restrict__ msum,
                 const float* __restrict__ deg,
                 const __bf16* __restrict__ Wn1T,
                 const float* __restrict__ bn1,
                 const __bf16* __restrict__ Wn2T,
                 const float* __restrict__ bn2,
                 float* __restrict__ xout) {
    __shared__ __align__(16) __bf16 Abf[64 * 264];
    __shared__ __align__(16) __bf16 Wt[128 * 56];
    __shared__ __align__(16) __bf16 A2[64 * 136];

    const int t = threadIdx.x;
    const int r0 = blockIdx.x * 64;
    const int w = t >> 6;
    const int lane = t & 63;
    const int m_ = lane & 15;
    const int q = lane >> 4;

    // stage A: cols 0..127 = x_bf16[row], 128..255 = bf16(m_sum[row]/deg)
    for (int i = 0; i < 8; ++i) {
        int id = t + 256 * i;
        int rl = id >> 5, ch = id & 31;
        int row = r0 + rl;
        int c8 = (ch & 15) * 8;
        union { __bf16 h[8]; uint4 u; } pk;
        if (row < NN) {
            if (ch < 16) {
                pk.u = *(const uint4*)(xb + (long)row * 128 + c8);
            } else {
                const float* mp = msum + (long)row * 128 + c8;
                float dg = deg[row]; dg = dg < 1.f ? 1.f : dg;
                float inv = 1.f / dg;
#pragma unroll
                for (int j = 0; j < 8; ++j) pk.h[j] = (__bf16)(mp[j] * inv);
            }
        } else {
            pk.u = make_uint4(0, 0, 0, 0);
        }
        *(uint4*)(Abf + rl * 264 + ((ch < 16) ? 0 : 128) + c8) = pk.u;
    }
    __syncthreads();

    f32x4_t acc[8];
#pragma unroll
    for (int ct = 0; ct < 8; ++ct) acc[ct] = (f32x4_t){0.f, 0.f, 0.f, 0.f};

    // layer 1: K=256
    for (int ks = 0; ks < 8; ++ks) {
#pragma unroll
        for (int i = 0; i < 2; ++i) {
            int c = t + 256 * i;
            int n = c >> 2, ko = (c & 3) * 8;
            uint4 v = *(const uint4*)(Wn1T + n * 256 + ks * 32 + ko);
            *(uint4*)(Wt + n * 56 + ko) = v;
        }
        __syncthreads();
        bf16x8_t a = *(const bf16x8_t*)(Abf + (w * 16 + m_) * 264 + ks * 32 + q * 8);
#pragma unroll
        for (int ct = 0; ct < 8; ++ct) {
            bf16x8_t b = *(const bf16x8_t*)(Wt + (ct * 16 + m_) * 56 + q * 8);
            acc[ct] = __builtin_amdgcn_mfma_f32_16x16x32_bf16(a, b, acc[ct], 0, 0, 0);
        }
        __syncthreads();
    }
#pragma unroll
    for (int ct = 0; ct < 8; ++ct) {
        int c = ct * 16 + m_;
        float b1 = bn1[c];
#pragma unroll
        for (int r = 0; r < 4; ++r) {
            int el = w * 16 + q * 4 + r;
            float v = acc[ct][r] + b1;
            A2[el * 136 + c] = (__bf16)silu_f(v);
        }
    }
    __syncthreads();

#pragma unroll
    for (int ct = 0; ct < 8; ++ct) acc[ct] = (f32x4_t){0.f, 0.f, 0.f, 0.f};

    // layer 2: K=128 (no activation)
    for (int ks = 0; ks < 4; ++ks) {
#pragma unroll
        for (int i = 0; i < 2; ++i) {
            int c = t + 256 * i;
            int n = c >> 2, ko = (c & 3) * 8;
            uint4 v = *(const uint4*)(Wn2T + n * 128 + ks * 32 + ko);
            *(uint4*)(Wt + n * 56 + ko) = v;
        }
        __syncthreads();
        bf16x8_t a = *(const bf16x8_t*)(A2 + (w * 16 + m_) * 136 + ks * 32 + q * 8);
#pragma unroll
        for (int ct = 0; ct < 8; ++ct) {
            bf16x8_t b = *(const bf16x8_t*)(Wt + (ct * 16 + m_) * 56 + q * 8);
            acc[ct] = __builtin_amdgcn_mfma_f32_16x16x32_bf16(a, b, acc[ct], 0, 0, 0);
        }
        __syncthreads();
    }
#pragma unroll
    for (int ct = 0; ct < 8; ++ct) {
        int c = ct * 16 + m_;
        float b2 = bn2[c];
#pragma unroll
        for (int r = 0; r < 4; ++r) {
            int el = w * 16 + q * 4 + r;
            int row = r0 + el;
            if (row < NN) xout[(long)row * 128 + c] = acc[ct][r] + b2;
        }
    }
}

// ---------------- pos update ----------------
__global__ void pos_kernel(const float* __restrict__ pos,
                           const float* __restrict__ coord,
                           const float* __restrict__ deg,
                           float* __restrict__ pout) {
    int i = blockIdx.x * blockDim.x + threadIdx.x;
    if (i < NN) {
        float d = deg[i]; d = d < 1.f ? 1.f : d;
        float inv = 1.f / d;
        pout[i * 3 + 0] = pos[i * 3 + 0] + coord[i * 3 + 0] * inv;
        pout[i * 3 + 1] = pos[i * 3 + 1] + coord[i * 3 + 1] * inv;
        pout[i * 3 + 2] = pos[i * 3 + 2] + coord[i * 3 + 2] * inv;
    }
}

extern "C" void kernel_launch(void* const* d_in, const int* in_sizes, int n_in,
                              void* d_out, int out_size, void* d_ws, size_t ws_size,
                              hipStream_t stream) {
    const float* x     = (const float*)d_in[0];
    const float* pos   = (const float*)d_in[1];
    const int*   eidx  = (const int*)d_in[2];
    const float* eattr = (const float*)d_in[3];
    const float* s     = (const float*)d_in[4];
    const float* We1   = (const float*)d_in[5];
    const float* be1   = (const float*)d_in[6];
    const float* We2   = (const float*)d_in[7];
    const float* be2   = (const float*)d_in[8];
    const float* Wn1   = (const float*)d_in[9];
    const float* bn1   = (const float*)d_in[10];
    const float* Wn2   = (const float*)d_in[11];
    const float* bn2   = (const float*)d_in[12];
    const float* Wc    = (const float*)d_in[13];
    const float* bc    = (const float*)d_in[14];

    char* ws = (char*)d_ws;
    __bf16* xb   = (__bf16*)(ws);                 // 12,800,000 B
    __bf16* We1T = (__bf16*)(ws + 12800000);      //     65,536
    __bf16* We2T = (__bf16*)(ws + 12865536);      //     32,768
    __bf16* Wn1T = (__bf16*)(ws + 12898304);      //     65,536
    __bf16* Wn2T = (__bf16*)(ws + 12963840);      //     32,768
    float*  msum = (float*)(ws + 12996608);       // 25,600,000
    float*  deg  = (float*)(ws + 38596608);       //    200,000
    float*  coord= (float*)(ws + 38796608);       //    600,000  (end 39,396,608)

    float* xout = (float*)d_out;
    float* pout = xout + (size_t)NN * 128;

    hipMemsetAsync(ws + 12996608, 0, 26400000, stream);  // msum + deg + coord
    prep_kernel<<<1024, 256, 0, stream>>>(x, We1, We2, Wn1, Wn2, xb, We1T, We2T, Wn1T, Wn2T);
    edge_kernel<<<EE / 64, 256, 0, stream>>>(xb, pos, eidx, eattr, s, We1T, We1, be1,
                                             We2T, be2, Wc, bc, msum, deg, coord);
    node_kernel<<<(NN + 63) / 64, 256, 0, stream>>>(xb, msum, deg, Wn1T, bn1, Wn2T, bn2, xout);
    pos_kernel<<<(NN + 255) / 256, 256, 0, stream>>>(pos, coord, deg, pout);
}

// Round 2
// 652.779 us; speedup vs baseline: 1.1501x; 1.1501x over previous
//
#include <hip/hip_runtime.h>
#include <hip/hip_bf16.h>

#define NN 50000
#define EE 800000
#define SCAN_BLOCKS 196   // 196*256 = 50176 >= NN

typedef __bf16 bf16x8_t __attribute__((ext_vector_type(8)));
typedef float f32x4_t __attribute__((ext_vector_type(4)));

__device__ __forceinline__ float silu_f(float v) {
    return v / (1.0f + __expf(-v));
}

// ---------------- prep: x -> bf16, weights -> transposed bf16 [n][k], dst histogram ----------------
__global__ void prep_kernel(const float* __restrict__ x,
                            const float* __restrict__ We1,
                            const float* __restrict__ We2,
                            const float* __restrict__ Wn1,
                            const float* __restrict__ Wn2,
                            const int* __restrict__ eidx,
                            __bf16* __restrict__ xb,
                            __bf16* __restrict__ We1T,
                            __bf16* __restrict__ We2T,
                            __bf16* __restrict__ Wn1T,
                            __bf16* __restrict__ Wn2T,
                            int* __restrict__ hist) {
    int tid = blockIdx.x * blockDim.x + threadIdx.x;
    int np = gridDim.x * blockDim.x;
    const int NX = NN * 128 / 4;
    for (int i = tid; i < NX; i += np) {
        float4 v = ((const float4*)x)[i];
        __bf16* o = xb + (size_t)i * 4;
        o[0] = (__bf16)v.x; o[1] = (__bf16)v.y; o[2] = (__bf16)v.z; o[3] = (__bf16)v.w;
    }
    for (int i = tid; i < 256 * 128; i += np) {
        int k = i >> 7, n = i & 127;
        We1T[n * 256 + k] = (__bf16)We1[i];
        Wn1T[n * 256 + k] = (__bf16)Wn1[i];
    }
    for (int i = tid; i < 128 * 128; i += np) {
        int k = i >> 7, n = i & 127;
        We2T[n * 128 + k] = (__bf16)We2[i];
        Wn2T[n * 128 + k] = (__bf16)Wn2[i];
    }
    for (int i = tid; i < EE; i += np) {
        atomicAdd(&hist[eidx[EE + i]], 1);
    }
}

// ---------------- counting-sort scan (3 tiny kernels) ----------------
__global__ void scan_a(const int* __restrict__ hist, int* __restrict__ bsum) {
    __shared__ int sh[256];
    int i = blockIdx.x * 256 + threadIdx.x;
    sh[threadIdx.x] = (i < NN) ? hist[i] : 0;
    __syncthreads();
    for (int s = 128; s > 0; s >>= 1) {
        if (threadIdx.x < s) sh[threadIdx.x] += sh[threadIdx.x + s];
        __syncthreads();
    }
    if (threadIdx.x == 0) bsum[blockIdx.x] = sh[0];
}

__global__ void scan_b(int* __restrict__ bsum) {
    __shared__ int sh[SCAN_BLOCKS];
    int t = threadIdx.x;
    if (t < SCAN_BLOCKS) sh[t] = bsum[t];
    __syncthreads();
    if (t == 0) {
        int acc = 0;
        for (int i = 0; i < SCAN_BLOCKS; ++i) { int v = sh[i]; sh[i] = acc; acc += v; }
    }
    __syncthreads();
    if (t < SCAN_BLOCKS) bsum[t] = sh[t];
}

__global__ void scan_c(const int* __restrict__ hist, const int* __restrict__ bsum,
                       int* __restrict__ off, int* __restrict__ cursor) {
    __shared__ int sh[256];
    int tx = threadIdx.x;
    int i = blockIdx.x * 256 + tx;
    int v = (i < NN) ? hist[i] : 0;
    sh[tx] = v;
    __syncthreads();
    for (int s = 1; s < 256; s <<= 1) {
        int add = (tx >= s) ? sh[tx - s] : 0;
        __syncthreads();
        sh[tx] += add;
        __syncthreads();
    }
    int excl = sh[tx] - v + bsum[blockIdx.x];
    if (i < NN) { off[i] = excl; cursor[i] = excl; }
    if (i == NN - 1) off[NN] = excl + v;
}

__global__ void scatter_kernel(const int* __restrict__ eidx, int* __restrict__ cursor,
                               int* __restrict__ perm) {
    int i = blockIdx.x * blockDim.x + threadIdx.x;
    if (i < EE) {
        int d = eidx[EE + i];
        int p = atomicAdd(&cursor[d], 1);
        perm[p] = i;
    }
}

// ---------------- edge kernel: gather + 2-layer MLP + gate + segmented scatter ----------------
// block = 256 threads (4 waves), tile = 64 sorted edges x 128 out cols
__global__ __launch_bounds__(256, 2)
void edge_kernel(const __bf16* __restrict__ xb,
                 const float* __restrict__ pos,
                 const int* __restrict__ eidx,
                 const float* __restrict__ eattr,
                 const float* __restrict__ s,
                 const int* __restrict__ perm,
                 const __bf16* __restrict__ We1T,
                 const float* __restrict__ We1,   // f32, rows 256/257 (r2, edge_attr)
                 const float* __restrict__ be1,
                 const __bf16* __restrict__ We2T,
                 const float* __restrict__ be2,
                 const float* __restrict__ Wc,
                 const float* __restrict__ bc,
                 float* __restrict__ msum,
                 float* __restrict__ coordsum) {
    __shared__ __align__(16) char Abuf_raw[64 * 264 * 2];   // A-tile bf16 (stride 264); later m f32 (stride 132)
    __shared__ __align__(16) __bf16 Wt[128 * 56];           // B tile [n][k], stride 56
    __shared__ __align__(16) __bf16 A2[64 * 136];           // layer-1 output, stride 136
    __shared__ float s_r2[64], s_ea[64], s_sg[64], s_diff[64 * 3], s_g[64];
    __shared__ int s_dst[64], s_eid[64];

    __bf16* Abf = (__bf16*)Abuf_raw;
    float* Mf = (float*)Abuf_raw;

    const int t = threadIdx.x;
    const int e0 = blockIdx.x * 64;
    const int w = t >> 6;
    const int lane = t & 63;
    const int m_ = lane & 15;
    const int q = lane >> 4;

    // per-edge scalars (sorted order via perm)
    if (t < 64) {
        int e = perm[e0 + t];
        s_eid[t] = e;
        int si = eidx[e];
        int di = eidx[EE + e];
        float dx = pos[di * 3 + 0] - pos[si * 3 + 0];
        float dy = pos[di * 3 + 1] - pos[si * 3 + 1];
        float dz = pos[di * 3 + 2] - pos[si * 3 + 2];
        s_diff[t * 3 + 0] = dx; s_diff[t * 3 + 1] = dy; s_diff[t * 3 + 2] = dz;
        s_r2[t] = dx * dx + dy * dy + dz * dz;
        s_ea[t] = eattr[e];
        s_sg[t] = s[si];
        s_dst[t] = di;
    }
    __syncthreads();

    // stage A: cols 0..127 = x[dst], 128..255 = x[src]  (bf16, 16B chunks)
    for (int i = 0; i < 8; ++i) {
        int id = t + 256 * i;          // 2048 = 64 edges * 32 chunks
        int el = id >> 5;
        int ch = id & 31;
        int e = s_eid[el];
        int node = (ch < 16) ? eidx[EE + e] : eidx[e];
        int c16 = ch & 15;
        uint4 v = *(const uint4*)(xb + (long)node * 128 + c16 * 8);
        *(uint4*)(Abf + el * 264 + ((ch < 16) ? 0 : 128) + c16 * 8) = v;
    }
    __syncthreads();

    f32x4_t acc[8];
#pragma unroll
    for (int ct = 0; ct < 8; ++ct) acc[ct] = (f32x4_t){0.f, 0.f, 0.f, 0.f};

    // ---- layer 1: [64,256] @ [256,128] ----
    for (int ks = 0; ks < 8; ++ks) {
#pragma unroll
        for (int i = 0; i < 2; ++i) {
            int c = t + 256 * i;
            int n = c >> 2, ko = (c & 3) * 8;
            uint4 v = *(const uint4*)(We1T + n * 256 + ks * 32 + ko);
            *(uint4*)(Wt + n * 56 + ko) = v;
        }
        __syncthreads();
        bf16x8_t a = *(const bf16x8_t*)(Abf + (w * 16 + m_) * 264 + ks * 32 + q * 8);
#pragma unroll
        for (int ct = 0; ct < 8; ++ct) {
            bf16x8_t b = *(const bf16x8_t*)(Wt + (ct * 16 + m_) * 56 + q * 8);
            acc[ct] = __builtin_amdgcn_mfma_f32_16x16x32_bf16(a, b, acc[ct], 0, 0, 0);
        }
        __syncthreads();
    }

    // epilogue 1: + b + r2*W[256] + ea*W[257], SiLU -> A2 (bf16)
#pragma unroll
    for (int ct = 0; ct < 8; ++ct) {
        int c = ct * 16 + m_;
        float w256 = We1[256 * 128 + c];
        float w257 = We1[257 * 128 + c];
        float b1 = be1[c];
#pragma unroll
        for (int r = 0; r < 4; ++r) {
            int el = w * 16 + q * 4 + r;
            float v = acc[ct][r] + b1 + s_r2[el] * w256 + s_ea[el] * w257;
            A2[el * 136 + c] = (__bf16)silu_f(v);
        }
    }
    __syncthreads();

#pragma unroll
    for (int ct = 0; ct < 8; ++ct) acc[ct] = (f32x4_t){0.f, 0.f, 0.f, 0.f};

    // ---- layer 2: [64,128] @ [128,128] ----
    for (int ks = 0; ks < 4; ++ks) {
#pragma unroll
        for (int i = 0; i < 2; ++i) {
            int c = t + 256 * i;
            int n = c >> 2, ko = (c & 3) * 8;
            uint4 v = *(const uint4*)(We2T + n * 128 + ks * 32 + ko);
            *(uint4*)(Wt + n * 56 + ko) = v;
        }
        __syncthreads();
        bf16x8_t a = *(const bf16x8_t*)(A2 + (w * 16 + m_) * 136 + ks * 32 + q * 8);
#pragma unroll
        for (int ct = 0; ct < 8; ++ct) {
            bf16x8_t b = *(const bf16x8_t*)(Wt + (ct * 16 + m_) * 56 + q * 8);
            acc[ct] = __builtin_amdgcn_mfma_f32_16x16x32_bf16(a, b, acc[ct], 0, 0, 0);
        }
        __syncthreads();
    }

    // epilogue 2: + b, SiLU, * s[src] -> Mf (f32, LDS); gamma via in-register shuffle reduce
    {
        float part0 = 0.f, part1 = 0.f, part2 = 0.f, part3 = 0.f;
#pragma unroll
        for (int ct = 0; ct < 8; ++ct) {
            int c = ct * 16 + m_;
            float b2 = be2[c];
            float wcv = Wc[c];
#pragma unroll
            for (int r = 0; r < 4; ++r) {
                int el = w * 16 + q * 4 + r;
                float v = silu_f(acc[ct][r] + b2) * s_sg[el];
                Mf[el * 132 + c] = v;
                float pv = v * wcv;
                if (r == 0) part0 += pv; else if (r == 1) part1 += pv;
                else if (r == 2) part2 += pv; else part3 += pv;
            }
        }
#pragma unroll
        for (int o = 1; o < 16; o <<= 1) {
            part0 += __shfl_xor(part0, o);
            part1 += __shfl_xor(part1, o);
            part2 += __shfl_xor(part2, o);
            part3 += __shfl_xor(part3, o);
        }
        if (m_ == 0) {
            float bc0 = bc[0];
            int el = w * 16 + q * 4;
            s_g[el + 0] = part0 + bc0;
            s_g[el + 1] = part1 + bc0;
            s_g[el + 2] = part2 + bc0;
            s_g[el + 3] = part3 + bc0;
        }
    }
    __syncthreads();

    // segmented reduction over sorted rows: one atomic per (group, col)
    if (t < 128) {
        int c = t;
        float run = 0.f;
        int cur = s_dst[0];
        for (int r = 0; r < 64; ++r) {
            int d = s_dst[r];                 // wave-uniform branch
            if (d != cur) {
                atomicAdd(&msum[(long)cur * 128 + c], run);
                run = 0.f; cur = d;
            }
            run += Mf[r * 132 + c];
        }
        atomicAdd(&msum[(long)cur * 128 + c], run);
    } else if (t < 131) {
        int axis = t - 128;
        float run = 0.f;
        int cur = s_dst[0];
        for (int r = 0; r < 64; ++r) {
            int d = s_dst[r];
            if (d != cur) {
                atomicAdd(&coordsum[cur * 3 + axis], run);
                run = 0.f; cur = d;
            }
            run += s_g[r] * s_diff[r * 3 + axis];
        }
        atomicAdd(&coordsum[cur * 3 + axis], run);
    }
}

// ---------------- node kernel: normalize agg + 2-layer node MLP ----------------
__global__ __launch_bounds__(256, 2)
void node_kernel(const __bf16* __restrict__ xb,
                 const float* __restrict__ msum,
                 const int* __restrict__ off,
                 const __bf16* __restrict__ Wn1T,
                 const float* __restrict__ bn1,
                 const __bf16* __restrict__ Wn2T,
                 const float* __restrict__ bn2,
                 float* __restrict__ xout) {
    __shared__ __align__(16) __bf16 Abf[64 * 264];
    __shared__ __align__(16) __bf16 Wt[128 * 56];
    __shared__ __align__(16) __bf16 A2[64 * 136];

    const int t = threadIdx.x;
    const int r0 = blockIdx.x * 64;
    const int w = t >> 6;
    const int lane = t & 63;
    const int m_ = lane & 15;
    const int q = lane >> 4;

    for (int i = 0; i < 8; ++i) {
        int id = t + 256 * i;
        int rl = id >> 5, ch = id & 31;
        int row = r0 + rl;
        int c8 = (ch & 15) * 8;
        union { __bf16 h[8]; uint4 u; } pk;
        if (row < NN) {
            if (ch < 16) {
                pk.u = *(const uint4*)(xb + (long)row * 128 + c8);
            } else {
                const float* mp = msum + (long)row * 128 + c8;
                int dg = off[row + 1] - off[row];
                float inv = 1.f / (float)(dg < 1 ? 1 : dg);
#pragma unroll
                for (int j = 0; j < 8; ++j) pk.h[j] = (__bf16)(mp[j] * inv);
            }
        } else {
            pk.u = make_uint4(0, 0, 0, 0);
        }
        *(uint4*)(Abf + rl * 264 + ((ch < 16) ? 0 : 128) + c8) = pk.u;
    }
    __syncthreads();

    f32x4_t acc[8];
#pragma unroll
    for (int ct = 0; ct < 8; ++ct) acc[ct] = (f32x4_t){0.f, 0.f, 0.f, 0.f};

    for (int ks = 0; ks < 8; ++ks) {
#pragma unroll
        for (int i = 0; i < 2; ++i) {
            int c = t + 256 * i;
            int n = c >> 2, ko = (c & 3) * 8;
            uint4 v = *(const uint4*)(Wn1T + n * 256 + ks * 32 + ko);
            *(uint4*)(Wt + n * 56 + ko) = v;
        }
        __syncthreads();
        bf16x8_t a = *(const bf16x8_t*)(Abf + (w * 16 + m_) * 264 + ks * 32 + q * 8);
#pragma unroll
        for (int ct = 0; ct < 8; ++ct) {
            bf16x8_t b = *(const bf16x8_t*)(Wt + (ct * 16 + m_) * 56 + q * 8);
            acc[ct] = __builtin_amdgcn_mfma_f32_16x16x32_bf16(a, b, acc[ct], 0, 0, 0);
        }
        __syncthreads();
    }
#pragma unroll
    for (int ct = 0; ct < 8; ++ct) {
        int c = ct * 16 + m_;
        float b1 = bn1[c];
#pragma unroll
        for (int r = 0; r < 4; ++r) {
            int el = w * 16 + q * 4 + r;
            float v = acc[ct][r] + b1;
            A2[el * 136 + c] = (__bf16)silu_f(v);
        }
    }
    __syncthreads();

#pragma unroll
    for (int ct = 0; ct < 8; ++ct) acc[ct] = (f32x4_t){0.f, 0.f, 0.f, 0.f};

    for (int ks = 0; ks < 4; ++ks) {
#pragma unroll
        for (int i = 0; i < 2; ++i) {
            int c = t + 256 * i;
            int n = c >> 2, ko = (c & 3) * 8;
            uint4 v = *(const uint4*)(Wn2T + n * 128 + ks * 32 + ko);
            *(uint4*)(Wt + n * 56 + ko) = v;
        }
        __syncthreads();
        bf16x8_t a = *(const bf16x8_t*)(A2 + (w * 16 + m_) * 136 + ks * 32 + q * 8);
#pragma unroll
        for (int ct = 0; ct < 8; ++ct) {
            bf16x8_t b = *(const bf16x8_t*)(Wt + (ct * 16 + m_) * 56 + q * 8);
            acc[ct] = __builtin_amdgcn_mfma_f32_16x16x32_bf16(a, b, acc[ct], 0, 0, 0);
        }
        __syncthreads();
    }
#pragma unroll
    for (int ct = 0; ct < 8; ++ct) {
        int c = ct * 16 + m_;
        float b2 = bn2[c];
#pragma unroll
        for (int r = 0; r < 4; ++r) {
            int el = w * 16 + q * 4 + r;
            int row = r0 + el;
            if (row < NN) xout[(long)row * 128 + c] = acc[ct][r] + b2;
        }
    }
}

// ---------------- pos update ----------------
__global__ void pos_kernel(const float* __restrict__ pos,
                           const float* __restrict__ coordsum,
                           const int* __restrict__ off,
                           float* __restrict__ pout) {
    int i = blockIdx.x * blockDim.x + threadIdx.x;
    if (i < NN) {
        int dg = off[i + 1] - off[i];
        float inv = 1.f / (float)(dg < 1 ? 1 : dg);
        pout[i * 3 + 0] = pos[i * 3 + 0] + coordsum[i * 3 + 0] * inv;
        pout[i * 3 + 1] = pos[i * 3 + 1] + coordsum[i * 3 + 1] * inv;
        pout[i * 3 + 2] = pos[i * 3 + 2] + coordsum[i * 3 + 2] * inv;
    }
}

extern "C" void kernel_launch(void* const* d_in, const int* in_sizes, int n_in,
                              void* d_out, int out_size, void* d_ws, size_t ws_size,
                              hipStream_t stream) {
    const float* x     = (const float*)d_in[0];
    const float* pos   = (const float*)d_in[1];
    const int*   eidx  = (const int*)d_in[2];
    const float* eattr = (const float*)d_in[3];
    const float* s     = (const float*)d_in[4];
    const float* We1   = (const float*)d_in[5];
    const float* be1   = (const float*)d_in[6];
    const float* We2   = (const float*)d_in[7];
    const float* be2   = (const float*)d_in[8];
    const float* Wn1   = (const float*)d_in[9];
    const float* bn1   = (const float*)d_in[10];
    const float* Wn2   = (const float*)d_in[11];
    const float* bn2   = (const float*)d_in[12];
    const float* Wc    = (const float*)d_in[13];
    const float* bc    = (const float*)d_in[14];

    char* ws = (char*)d_ws;
    __bf16* xb    = (__bf16*)(ws);                 // 12,800,000
    __bf16* We1T  = (__bf16*)(ws + 12800000);      //     65,536
    __bf16* We2T  = (__bf16*)(ws + 12865536);      //     32,768
    __bf16* Wn1T  = (__bf16*)(ws + 12898304);      //     65,536
    __bf16* Wn2T  = (__bf16*)(ws + 12963840);      //     32,768
    float*  msum  = (float*)(ws + 12996608);       // 25,600,000
    float*  csum  = (float*)(ws + 38596608);       //    600,000
    int*    hist  = (int*)(ws + 39196608);         //    200,000
    int*    off   = (int*)(ws + 39396608);         //    200,016 (NN+1 ints, padded)
    int*    cursor= (int*)(ws + 39596624);         //    200,000
    int*    perm  = (int*)(ws + 39796624);         //  3,200,000
    int*    bsum  = (int*)(ws + 42996624);         //      1,024  (end 42,997,648)

    float* xout = (float*)d_out;
    float* pout = xout + (size_t)NN * 128;

    // zero msum + coordsum + hist (contiguous, 26.4 MB)
    hipMemsetAsync(ws + 12996608, 0, 26400000, stream);
    prep_kernel<<<1024, 256, 0, stream>>>(x, We1, We2, Wn1, Wn2, eidx,
                                          xb, We1T, We2T, Wn1T, Wn2T, hist);
    scan_a<<<SCAN_BLOCKS, 256, 0, stream>>>(hist, bsum);
    scan_b<<<1, 256, 0, stream>>>(bsum);
    scan_c<<<SCAN_BLOCKS, 256, 0, stream>>>(hist, bsum, off, cursor);
    scatter_kernel<<<(EE + 255) / 256, 256, 0, stream>>>(eidx, cursor, perm);
    edge_kernel<<<EE / 64, 256, 0, stream>>>(xb, pos, eidx, eattr, s, perm,
                                             We1T, We1, be1, We2T, be2, Wc, bc,
                                             msum, csum);
    node_kernel<<<(NN + 63) / 64, 256, 0, stream>>>(xb, msum, off, Wn1T, bn1, Wn2T, bn2, xout);
    pos_kernel<<<(NN + 255) / 256, 256, 0, stream>>>(pos, csum, off, pout);
}

// Round 3
// 491.006 us; speedup vs baseline: 1.5290x; 1.3295x over previous
//
#include <hip/hip_runtime.h>
#include <hip/hip_bf16.h>

#define NN 50000
#define EE 800000
#define SCAN_BLOCKS 196   // 196*256 = 50176 >= NN

typedef __bf16 bf16x8_t __attribute__((ext_vector_type(8)));
typedef float f32x4_t __attribute__((ext_vector_type(4)));

__device__ __forceinline__ float silu_f(float v) {
    return v / (1.0f + __expf(-v));
}

// ---------------- prep: x -> bf16, weights -> transposed bf16 [n][k], dst histogram ----------------
__global__ void prep_kernel(const float* __restrict__ x,
                            const float* __restrict__ We1,
                            const float* __restrict__ We2,
                            const float* __restrict__ Wn1,
                            const float* __restrict__ Wn2,
                            const int* __restrict__ eidx,
                            __bf16* __restrict__ xb,
                            __bf16* __restrict__ We1T,
                            __bf16* __restrict__ We2T,
                            __bf16* __restrict__ Wn1T,
                            __bf16* __restrict__ Wn2T,
                            int* __restrict__ hist) {
    int tid = blockIdx.x * blockDim.x + threadIdx.x;
    int np = gridDim.x * blockDim.x;
    const int NX = NN * 128 / 4;
    for (int i = tid; i < NX; i += np) {
        float4 v = ((const float4*)x)[i];
        __bf16* o = xb + (size_t)i * 4;
        o[0] = (__bf16)v.x; o[1] = (__bf16)v.y; o[2] = (__bf16)v.z; o[3] = (__bf16)v.w;
    }
    for (int i = tid; i < 256 * 128; i += np) {
        int k = i >> 7, n = i & 127;
        We1T[n * 256 + k] = (__bf16)We1[i];
        Wn1T[n * 256 + k] = (__bf16)Wn1[i];
    }
    for (int i = tid; i < 128 * 128; i += np) {
        int k = i >> 7, n = i & 127;
        We2T[n * 128 + k] = (__bf16)We2[i];
        Wn2T[n * 128 + k] = (__bf16)Wn2[i];
    }
    for (int i = tid; i < EE; i += np) {
        atomicAdd(&hist[eidx[EE + i]], 1);
    }
}

// ---------------- counting-sort scan (3 tiny kernels) ----------------
__global__ void scan_a(const int* __restrict__ hist, int* __restrict__ bsum) {
    __shared__ int sh[256];
    int i = blockIdx.x * 256 + threadIdx.x;
    sh[threadIdx.x] = (i < NN) ? hist[i] : 0;
    __syncthreads();
    for (int s = 128; s > 0; s >>= 1) {
        if (threadIdx.x < s) sh[threadIdx.x] += sh[threadIdx.x + s];
        __syncthreads();
    }
    if (threadIdx.x == 0) bsum[blockIdx.x] = sh[0];
}

__global__ void scan_b(int* __restrict__ bsum) {
    __shared__ int sh[SCAN_BLOCKS];
    int t = threadIdx.x;
    if (t < SCAN_BLOCKS) sh[t] = bsum[t];
    __syncthreads();
    if (t == 0) {
        int acc = 0;
        for (int i = 0; i < SCAN_BLOCKS; ++i) { int v = sh[i]; sh[i] = acc; acc += v; }
    }
    __syncthreads();
    if (t < SCAN_BLOCKS) bsum[t] = sh[t];
}

__global__ void scan_c(const int* __restrict__ hist, const int* __restrict__ bsum,
                       int* __restrict__ off, int* __restrict__ cursor) {
    __shared__ int sh[256];
    int tx = threadIdx.x;
    int i = blockIdx.x * 256 + tx;
    int v = (i < NN) ? hist[i] : 0;
    sh[tx] = v;
    __syncthreads();
    for (int s = 1; s < 256; s <<= 1) {
        int add = (tx >= s) ? sh[tx - s] : 0;
        __syncthreads();
        sh[tx] += add;
        __syncthreads();
    }
    int excl = sh[tx] - v + bsum[blockIdx.x];
    if (i < NN) { off[i] = excl; cursor[i] = excl; }
    if (i == NN - 1) off[NN] = excl + v;
}

__global__ void scatter_kernel(const int* __restrict__ eidx, int* __restrict__ cursor,
                               int* __restrict__ perm) {
    int i = blockIdx.x * blockDim.x + threadIdx.x;
    if (i < EE) {
        int d = eidx[EE + i];
        int p = atomicAdd(&cursor[d], 1);
        perm[p] = i;
    }
}

// ---------------- edge kernel v3: operand-swapped MFMA, no A-tile staging ----------------
// block = 256 threads (4 waves), tile = 128 sorted edges.
// D = W * X^T : A-operand = weight tile [outcol][k] (LDS, per-k-slice),
//               B-operand = gathered x rows, 16B direct global loads.
// Result layout: lane(m_,q) holds edge = et_base + m_, outcols = ot*16 + q*4 + {0..3}.
__global__ __launch_bounds__(256, 3)
void edge_kernel(const __bf16* __restrict__ xb,
                 const float* __restrict__ pos,
                 const int* __restrict__ eidx,
                 const float* __restrict__ eattr,
                 const float* __restrict__ s,
                 const int* __restrict__ perm,
                 const __bf16* __restrict__ We1T,
                 const float* __restrict__ We1,   // f32, rows 256/257 (r2, edge_attr)
                 const float* __restrict__ be1,
                 const __bf16* __restrict__ We2T,
                 const float* __restrict__ be2,
                 const float* __restrict__ Wc,
                 const float* __restrict__ bc,
                 float* __restrict__ msum,
                 float* __restrict__ coordsum) {
    __shared__ __align__(16) __bf16 Wt[128 * 32];   //  8,192 B: weight k-slice [outcol][32]
    __shared__ __align__(16) __bf16 A2[128 * 136];  // 34,816 B; Mf (f32 64x132 = 33,792) aliases
    __shared__ float s_r2[128], s_ea[128], s_sg[128], s_g[128];
    __shared__ float s_diff[128 * 3];
    __shared__ int s_dst[128], s_src[128];

    float* Mf = (float*)A2;

    const int t = threadIdx.x;
    const int e0 = blockIdx.x * 128;
    const int w = t >> 6;
    const int lane = t & 63;
    const int m_ = lane & 15;
    const int q = lane >> 4;

    // per-edge scalars (sorted order via perm)
    if (t < 128) {
        int e = perm[e0 + t];
        int si = eidx[e];
        int di = eidx[EE + e];
        float dx = pos[di * 3 + 0] - pos[si * 3 + 0];
        float dy = pos[di * 3 + 1] - pos[si * 3 + 1];
        float dz = pos[di * 3 + 2] - pos[si * 3 + 2];
        s_diff[t * 3 + 0] = dx; s_diff[t * 3 + 1] = dy; s_diff[t * 3 + 2] = dz;
        s_r2[t] = dx * dx + dy * dy + dz * dz;
        s_ea[t] = eattr[e];
        s_sg[t] = s[si];
        s_dst[t] = di;
        s_src[t] = si;
    }
    __syncthreads();

    const int el0 = w * 16 + m_;          // this lane's edge (tile 0), local index
    const int el1 = 64 + w * 16 + m_;     // tile 1
    const int nd0 = s_dst[el0], ns0 = s_src[el0];
    const int nd1 = s_dst[el1], ns1 = s_src[el1];

    f32x4_t acc[2][8];
#pragma unroll
    for (int et = 0; et < 2; ++et)
#pragma unroll
        for (int ot = 0; ot < 8; ++ot) acc[et][ot] = (f32x4_t){0.f, 0.f, 0.f, 0.f};

    const int wrow = t >> 2;              // staging: outcol for chunk t
    const int wpart = (t & 3) * 8;

    // ---- layer 1: K = 256 (cols 0..127 = x[dst], 128..255 = x[src]) ----
    for (int ks = 0; ks < 8; ++ks) {
        int col = (ks & 3) * 32 + q * 8;
        // B-fragments: direct global 16B loads (issued before the barrier)
        bf16x8_t xf0 = *(const bf16x8_t*)(xb + (long)(ks < 4 ? nd0 : ns0) * 128 + col);
        bf16x8_t xf1 = *(const bf16x8_t*)(xb + (long)(ks < 4 ? nd1 : ns1) * 128 + col);
        // weight slice staging loads (constant source, safe to hoist)
        uint4 v0 = *(const uint4*)(We1T + wrow * 256 + ks * 32 + wpart);
        uint4 v1 = *(const uint4*)(We1T + (wrow + 64) * 256 + ks * 32 + wpart);
        __syncthreads();                                   // prev compute done with Wt
        *(uint4*)(Wt + wrow * 32 + wpart) = v0;
        *(uint4*)(Wt + (wrow + 64) * 32 + wpart) = v1;
        __syncthreads();                                   // Wt ready
#pragma unroll
        for (int ot = 0; ot < 8; ++ot) {
            bf16x8_t wf = *(const bf16x8_t*)(Wt + (ot * 16 + m_) * 32 + q * 8);
            acc[0][ot] = __builtin_amdgcn_mfma_f32_16x16x32_bf16(wf, xf0, acc[0][ot], 0, 0, 0);
            acc[1][ot] = __builtin_amdgcn_mfma_f32_16x16x32_bf16(wf, xf1, acc[1][ot], 0, 0, 0);
        }
    }

    // epilogue 1: + b + r2*W[256] + ea*W[257], SiLU -> A2 (bf16, packed b64 writes)
#pragma unroll
    for (int et = 0; et < 2; ++et) {
        int e = et ? el1 : el0;
        float r2 = s_r2[e], ea = s_ea[e];
#pragma unroll
        for (int ot = 0; ot < 8; ++ot) {
            int oc = ot * 16 + q * 4;
            float4 b1 = *(const float4*)(be1 + oc);
            float4 w6 = *(const float4*)(We1 + 256 * 128 + oc);
            float4 w7 = *(const float4*)(We1 + 257 * 128 + oc);
            union { __bf16 h[4]; uint2 u2; } pk;
            pk.h[0] = (__bf16)silu_f(acc[et][ot][0] + b1.x + r2 * w6.x + ea * w7.x);
            pk.h[1] = (__bf16)silu_f(acc[et][ot][1] + b1.y + r2 * w6.y + ea * w7.y);
            pk.h[2] = (__bf16)silu_f(acc[et][ot][2] + b1.z + r2 * w6.z + ea * w7.z);
            pk.h[3] = (__bf16)silu_f(acc[et][ot][3] + b1.w + r2 * w6.w + ea * w7.w);
            *(uint2*)(A2 + e * 136 + oc) = pk.u2;
        }
    }
    // NOTE: each wave reads back only its own A2 rows; the barrier inside the
    // layer-2 loop (before Wt overwrite) orders A2 writes vs reads anyway.

#pragma unroll
    for (int et = 0; et < 2; ++et)
#pragma unroll
        for (int ot = 0; ot < 8; ++ot) acc[et][ot] = (f32x4_t){0.f, 0.f, 0.f, 0.f};

    // ---- layer 2: K = 128, B-operand = A2 rows (same-wave LDS) ----
    for (int ks = 0; ks < 4; ++ks) {
        uint4 v0 = *(const uint4*)(We2T + wrow * 128 + ks * 32 + wpart);
        uint4 v1 = *(const uint4*)(We2T + (wrow + 64) * 128 + ks * 32 + wpart);
        __syncthreads();
        *(uint4*)(Wt + wrow * 32 + wpart) = v0;
        *(uint4*)(Wt + (wrow + 64) * 32 + wpart) = v1;
        __syncthreads();
        bf16x8_t af0 = *(const bf16x8_t*)(A2 + el0 * 136 + ks * 32 + q * 8);
        bf16x8_t af1 = *(const bf16x8_t*)(A2 + el1 * 136 + ks * 32 + q * 8);
#pragma unroll
        for (int ot = 0; ot < 8; ++ot) {
            bf16x8_t wf = *(const bf16x8_t*)(Wt + (ot * 16 + m_) * 32 + q * 8);
            acc[0][ot] = __builtin_amdgcn_mfma_f32_16x16x32_bf16(wf, af0, acc[0][ot], 0, 0, 0);
            acc[1][ot] = __builtin_amdgcn_mfma_f32_16x16x32_bf16(wf, af1, acc[1][ot], 0, 0, 0);
        }
    }

    // epilogue 2: + b, SiLU, * s[src] (in place); gamma via q-lane shuffle reduce
    {
        float sg0 = s_sg[el0], sg1 = s_sg[el1];
        float gp0 = 0.f, gp1 = 0.f;
#pragma unroll
        for (int ot = 0; ot < 8; ++ot) {
            int oc = ot * 16 + q * 4;
            float4 b2 = *(const float4*)(be2 + oc);
            float4 wc = *(const float4*)(Wc + oc);
            f32x4_t v0 = acc[0][ot], v1 = acc[1][ot];
            v0[0] = silu_f(v0[0] + b2.x) * sg0; v0[1] = silu_f(v0[1] + b2.y) * sg0;
            v0[2] = silu_f(v0[2] + b2.z) * sg0; v0[3] = silu_f(v0[3] + b2.w) * sg0;
            v1[0] = silu_f(v1[0] + b2.x) * sg1; v1[1] = silu_f(v1[1] + b2.y) * sg1;
            v1[2] = silu_f(v1[2] + b2.z) * sg1; v1[3] = silu_f(v1[3] + b2.w) * sg1;
            acc[0][ot] = v0; acc[1][ot] = v1;
            gp0 += v0[0] * wc.x + v0[1] * wc.y + v0[2] * wc.z + v0[3] * wc.w;
            gp1 += v1[0] * wc.x + v1[1] * wc.y + v1[2] * wc.z + v1[3] * wc.w;
        }
        gp0 += __shfl_xor(gp0, 16); gp0 += __shfl_xor(gp0, 32);
        gp1 += __shfl_xor(gp1, 16); gp1 += __shfl_xor(gp1, 32);
        if (q == 0) {
            float b0 = bc[0];
            s_g[el0] = gp0 + b0;
            s_g[el1] = gp1 + b0;
        }
    }
    __syncthreads();   // P0: all A2 reads done (Mf may alias), s_g visible

    // two phases of 64 edges each: Mf stage (b128, conflict-free) + segmented reduce
#pragma unroll
    for (int ph = 0; ph < 2; ++ph) {
        int lr = w * 16 + m_;
#pragma unroll
        for (int ot = 0; ot < 8; ++ot)
            *(f32x4_t*)(Mf + lr * 132 + ot * 16 + q * 4) = acc[ph][ot];
        __syncthreads();   // Mf complete
        if (t < 128) {
            float run = 0.f;
            int cur = s_dst[ph * 64];
            for (int r = 0; r < 64; ++r) {
                int d = s_dst[ph * 64 + r];       // wave-uniform branch
                if (d != cur) {
                    atomicAdd(&msum[(long)cur * 128 + t], run);
                    run = 0.f; cur = d;
                }
                run += Mf[r * 132 + t];
            }
            atomicAdd(&msum[(long)cur * 128 + t], run);
        } else if (t < 131) {
            int ax = t - 128;
            float run = 0.f;
            int cur = s_dst[ph * 64];
            for (int r = 0; r < 64; ++r) {
                int rr = ph * 64 + r;
                int d = s_dst[rr];
                if (d != cur) {
                    atomicAdd(&coordsum[cur * 3 + ax], run);
                    run = 0.f; cur = d;
                }
                run += s_g[rr] * s_diff[rr * 3 + ax];
            }
            atomicAdd(&coordsum[cur * 3 + ax], run);
        }
        __syncthreads();   // reduce done before Mf overwrite / exit
    }
}

// ---------------- node kernel: normalize agg + 2-layer node MLP ----------------
__global__ __launch_bounds__(256, 2)
void node_kernel(const __bf16* __restrict__ xb,
                 const float* __restrict__ msum,
                 const int* __restrict__ off,
                 const __bf16* __restrict__ Wn1T,
                 const float* __restrict__ bn1,
                 const __bf16* __restrict__ Wn2T,
                 const float* __restrict__ bn2,
                 float* __restrict__ xout) {
    __shared__ __align__(16) __bf16 Abf[64 * 264];
    __shared__ __align__(16) __bf16 Wt[128 * 56];
    __shared__ __align__(16) __bf16 A2[64 * 136];

    const int t = threadIdx.x;
    const int r0 = blockIdx.x * 64;
    const int w = t >> 6;
    const int lane = t & 63;
    const int m_ = lane & 15;
    const int q = lane >> 4;

    for (int i = 0; i < 8; ++i) {
        int id = t + 256 * i;
        int rl = id >> 5, ch = id & 31;
        int row = r0 + rl;
        int c8 = (ch & 15) * 8;
        union { __bf16 h[8]; uint4 u; } pk;
        if (row < NN) {
            if (ch < 16) {
                pk.u = *(const uint4*)(xb + (long)row * 128 + c8);
            } else {
                const float* mp = msum + (long)row * 128 + c8;
                int dg = off[row + 1] - off[row];
                float inv = 1.f / (float)(dg < 1 ? 1 : dg);
#pragma unroll
                for (int j = 0; j < 8; ++j) pk.h[j] = (__bf16)(mp[j] * inv);
            }
        } else {
            pk.u = make_uint4(0, 0, 0, 0);
        }
        *(uint4*)(Abf + rl * 264 + ((ch < 16) ? 0 : 128) + c8) = pk.u;
    }
    __syncthreads();

    f32x4_t acc[8];
#pragma unroll
    for (int ct = 0; ct < 8; ++ct) acc[ct] = (f32x4_t){0.f, 0.f, 0.f, 0.f};

    for (int ks = 0; ks < 8; ++ks) {
#pragma unroll
        for (int i = 0; i < 2; ++i) {
            int c = t + 256 * i;
            int n = c >> 2, ko = (c & 3) * 8;
            uint4 v = *(const uint4*)(Wn1T + n * 256 + ks * 32 + ko);
            *(uint4*)(Wt + n * 56 + ko) = v;
        }
        __syncthreads();
        bf16x8_t a = *(const bf16x8_t*)(Abf + (w * 16 + m_) * 264 + ks * 32 + q * 8);
#pragma unroll
        for (int ct = 0; ct < 8; ++ct) {
            bf16x8_t b = *(const bf16x8_t*)(Wt + (ct * 16 + m_) * 56 + q * 8);
            acc[ct] = __builtin_amdgcn_mfma_f32_16x16x32_bf16(a, b, acc[ct], 0, 0, 0);
        }
        __syncthreads();
    }
#pragma unroll
    for (int ct = 0; ct < 8; ++ct) {
        int c = ct * 16 + m_;
        float b1 = bn1[c];
#pragma unroll
        for (int r = 0; r < 4; ++r) {
            int el = w * 16 + q * 4 + r;
            float v = acc[ct][r] + b1;
            A2[el * 136 + c] = (__bf16)silu_f(v);
        }
    }
    __syncthreads();

#pragma unroll
    for (int ct = 0; ct < 8; ++ct) acc[ct] = (f32x4_t){0.f, 0.f, 0.f, 0.f};

    for (int ks = 0; ks < 4; ++ks) {
#pragma unroll
        for (int i = 0; i < 2; ++i) {
            int c = t + 256 * i;
            int n = c >> 2, ko = (c & 3) * 8;
            uint4 v = *(const uint4*)(Wn2T + n * 128 + ks * 32 + ko);
            *(uint4*)(Wt + n * 56 + ko) = v;
        }
        __syncthreads();
        bf16x8_t a = *(const bf16x8_t*)(A2 + (w * 16 + m_) * 136 + ks * 32 + q * 8);
#pragma unroll
        for (int ct = 0; ct < 8; ++ct) {
            bf16x8_t b = *(const bf16x8_t*)(Wt + (ct * 16 + m_) * 56 + q * 8);
            acc[ct] = __builtin_amdgcn_mfma_f32_16x16x32_bf16(a, b, acc[ct], 0, 0, 0);
        }
        __syncthreads();
    }
#pragma unroll
    for (int ct = 0; ct < 8; ++ct) {
        int c = ct * 16 + m_;
        float b2 = bn2[c];
#pragma unroll
        for (int r = 0; r < 4; ++r) {
            int el = w * 16 + q * 4 + r;
            int row = r0 + el;
            if (row < NN) xout[(long)row * 128 + c] = acc[ct][r] + b2;
        }
    }
}

// ---------------- pos update ----------------
__global__ void pos_kernel(const float* __restrict__ pos,
                           const float* __restrict__ coordsum,
                           const int* __restrict__ off,
                           float* __restrict__ pout) {
    int i = blockIdx.x * blockDim.x + threadIdx.x;
    if (i < NN) {
        int dg = off[i + 1] - off[i];
        float inv = 1.f / (float)(dg < 1 ? 1 : dg);
        pout[i * 3 + 0] = pos[i * 3 + 0] + coordsum[i * 3 + 0] * inv;
        pout[i * 3 + 1] = pos[i * 3 + 1] + coordsum[i * 3 + 1] * inv;
        pout[i * 3 + 2] = pos[i * 3 + 2] + coordsum[i * 3 + 2] * inv;
    }
}

extern "C" void kernel_launch(void* const* d_in, const int* in_sizes, int n_in,
                              void* d_out, int out_size, void* d_ws, size_t ws_size,
                              hipStream_t stream) {
    const float* x     = (const float*)d_in[0];
    const float* pos   = (const float*)d_in[1];
    const int*   eidx  = (const int*)d_in[2];
    const float* eattr = (const float*)d_in[3];
    const float* s     = (const float*)d_in[4];
    const float* We1   = (const float*)d_in[5];
    const float* be1   = (const float*)d_in[6];
    const float* We2   = (const float*)d_in[7];
    const float* be2   = (const float*)d_in[8];
    const float* Wn1   = (const float*)d_in[9];
    const float* bn1   = (const float*)d_in[10];
    const float* Wn2   = (const float*)d_in[11];
    const float* bn2   = (const float*)d_in[12];
    const float* Wc    = (const float*)d_in[13];
    const float* bc    = (const float*)d_in[14];

    char* ws = (char*)d_ws;
    __bf16* xb    = (__bf16*)(ws);                 // 12,800,000
    __bf16* We1T  = (__bf16*)(ws + 12800000);      //     65,536
    __bf16* We2T  = (__bf16*)(ws + 12865536);      //     32,768
    __bf16* Wn1T  = (__bf16*)(ws + 12898304);      //     65,536
    __bf16* Wn2T  = (__bf16*)(ws + 12963840);      //     32,768
    float*  msum  = (float*)(ws + 12996608);       // 25,600,000
    float*  csum  = (float*)(ws + 38596608);       //    600,000
    int*    hist  = (int*)(ws + 39196608);         //    200,000
    int*    off   = (int*)(ws + 39396608);         //    200,016 (NN+1 ints, padded)
    int*    cursor= (int*)(ws + 39596624);         //    200,000
    int*    perm  = (int*)(ws + 39796624);         //  3,200,000
    int*    bsum  = (int*)(ws + 42996624);         //      1,024  (end 42,997,648)

    float* xout = (float*)d_out;
    float* pout = xout + (size_t)NN * 128;

    // zero msum + coordsum + hist (contiguous, 26.4 MB)
    hipMemsetAsync(ws + 12996608, 0, 26400000, stream);
    prep_kernel<<<1024, 256, 0, stream>>>(x, We1, We2, Wn1, Wn2, eidx,
                                          xb, We1T, We2T, Wn1T, Wn2T, hist);
    scan_a<<<SCAN_BLOCKS, 256, 0, stream>>>(hist, bsum);
    scan_b<<<1, 256, 0, stream>>>(bsum);
    scan_c<<<SCAN_BLOCKS, 256, 0, stream>>>(hist, bsum, off, cursor);
    scatter_kernel<<<(EE + 255) / 256, 256, 0, stream>>>(eidx, cursor, perm);
    edge_kernel<<<EE / 128, 256, 0, stream>>>(xb, pos, eidx, eattr, s, perm,
                                              We1T, We1, be1, We2T, be2, Wc, bc,
                                              msum, csum);
    node_kernel<<<(NN + 63) / 64, 256, 0, stream>>>(xb, msum, off, Wn1T, bn1, Wn2T, bn2, xout);
    pos_kernel<<<(NN + 255) / 256, 256, 0, stream>>>(pos, csum, off, pout);
}

// Round 4
// 451.806 us; speedup vs baseline: 1.6617x; 1.0868x over previous
//
#include <hip/hip_runtime.h>
#include <hip/hip_bf16.h>

#define NN 50000
#define EE 800000
#define SCAN_BLOCKS 196   // 196*256 = 50176 >= NN

typedef __bf16 bf16x8_t __attribute__((ext_vector_type(8)));
typedef float f32x4_t __attribute__((ext_vector_type(4)));

__device__ __forceinline__ float silu_f(float v) {
    // v * 1/(1+exp(-v)) with v_rcp_f32 (avoids the ~9-instr precise-div sequence)
    return v * __builtin_amdgcn_rcpf(1.0f + __expf(-v));
}

// ---------------- prep: x -> bf16, weights -> transposed bf16 [n][k], dst histogram ----------------
__global__ void prep_kernel(const float* __restrict__ x,
                            const float* __restrict__ We1,
                            const float* __restrict__ We2,
                            const float* __restrict__ Wn1,
                            const float* __restrict__ Wn2,
                            const int* __restrict__ eidx,
                            __bf16* __restrict__ xb,
                            __bf16* __restrict__ We1T,
                            __bf16* __restrict__ We2T,
                            __bf16* __restrict__ Wn1T,
                            __bf16* __restrict__ Wn2T,
                            int* __restrict__ hist) {
    int tid = blockIdx.x * blockDim.x + threadIdx.x;
    int np = gridDim.x * blockDim.x;
    const int NX = NN * 128 / 4;
    for (int i = tid; i < NX; i += np) {
        float4 v = ((const float4*)x)[i];
        __bf16* o = xb + (size_t)i * 4;
        o[0] = (__bf16)v.x; o[1] = (__bf16)v.y; o[2] = (__bf16)v.z; o[3] = (__bf16)v.w;
    }
    for (int i = tid; i < 256 * 128; i += np) {
        int k = i >> 7, n = i & 127;
        We1T[n * 256 + k] = (__bf16)We1[i];
        Wn1T[n * 256 + k] = (__bf16)Wn1[i];
    }
    for (int i = tid; i < 128 * 128; i += np) {
        int k = i >> 7, n = i & 127;
        We2T[n * 128 + k] = (__bf16)We2[i];
        Wn2T[n * 128 + k] = (__bf16)Wn2[i];
    }
    for (int i = tid; i < EE; i += np) {
        atomicAdd(&hist[eidx[EE + i]], 1);
    }
}

// ---------------- counting-sort scan (3 tiny kernels) ----------------
__global__ void scan_a(const int* __restrict__ hist, int* __restrict__ bsum) {
    __shared__ int sh[256];
    int i = blockIdx.x * 256 + threadIdx.x;
    sh[threadIdx.x] = (i < NN) ? hist[i] : 0;
    __syncthreads();
    for (int s = 128; s > 0; s >>= 1) {
        if (threadIdx.x < s) sh[threadIdx.x] += sh[threadIdx.x + s];
        __syncthreads();
    }
    if (threadIdx.x == 0) bsum[blockIdx.x] = sh[0];
}

__global__ void scan_b(int* __restrict__ bsum) {
    __shared__ int sh[SCAN_BLOCKS];
    int t = threadIdx.x;
    if (t < SCAN_BLOCKS) sh[t] = bsum[t];
    __syncthreads();
    if (t == 0) {
        int acc = 0;
        for (int i = 0; i < SCAN_BLOCKS; ++i) { int v = sh[i]; sh[i] = acc; acc += v; }
    }
    __syncthreads();
    if (t < SCAN_BLOCKS) bsum[t] = sh[t];
}

__global__ void scan_c(const int* __restrict__ hist, const int* __restrict__ bsum,
                       int* __restrict__ off, int* __restrict__ cursor) {
    __shared__ int sh[256];
    int tx = threadIdx.x;
    int i = blockIdx.x * 256 + tx;
    int v = (i < NN) ? hist[i] : 0;
    sh[tx] = v;
    __syncthreads();
    for (int s = 1; s < 256; s <<= 1) {
        int add = (tx >= s) ? sh[tx - s] : 0;
        __syncthreads();
        sh[tx] += add;
        __syncthreads();
    }
    int excl = sh[tx] - v + bsum[blockIdx.x];
    if (i < NN) { off[i] = excl; cursor[i] = excl; }
    if (i == NN - 1) off[NN] = excl + v;
}

// ---------------- scatter: build sorted per-edge records (no indirection in edge kernel) ----------------
__global__ void scatter_kernel(const int* __restrict__ eidx,
                               const float* __restrict__ pos,
                               const float* __restrict__ eattr,
                               const float* __restrict__ s,
                               int* __restrict__ cursor,
                               float4* __restrict__ e_geo,
                               int2* __restrict__ e_nodes,
                               float2* __restrict__ e_gate) {
    int i = blockIdx.x * blockDim.x + threadIdx.x;
    if (i < EE) {
        int si = eidx[i];
        int di = eidx[EE + i];
        int p = atomicAdd(&cursor[di], 1);
        float dx = pos[di * 3 + 0] - pos[si * 3 + 0];
        float dy = pos[di * 3 + 1] - pos[si * 3 + 1];
        float dz = pos[di * 3 + 2] - pos[si * 3 + 2];
        e_geo[p] = make_float4(dx, dy, dz, dx * dx + dy * dy + dz * dz);
        e_nodes[p] = make_int2(si, di);
        e_gate[p] = make_float2(eattr[i], s[si]);
    }
}

// ---------------- edge kernel v4: operand-swapped MFMA + fast silu + parallel reduce ----------------
// block = 256 threads (4 waves), tile = 128 sorted edges.
// D = W * X^T : A-operand = weight k-slice in LDS, B-operand = 16B direct global x loads.
// Result: lane(m_,q) holds edge w*16+m_ (+64 for tile 1), outcols ot*16+q*4+{0..3}.
__global__ __launch_bounds__(256, 3)
void edge_kernel(const __bf16* __restrict__ xb,
                 const float4* __restrict__ e_geo,
                 const int2* __restrict__ e_nodes,
                 const float2* __restrict__ e_gate,
                 const __bf16* __restrict__ We1T,
                 const float* __restrict__ We1,   // f32, rows 256/257 (r2, edge_attr)
                 const float* __restrict__ be1,
                 const __bf16* __restrict__ We2T,
                 const float* __restrict__ be2,
                 const float* __restrict__ Wc,
                 const float* __restrict__ bc,
                 float* __restrict__ msum,
                 float* __restrict__ coordsum) {
    __shared__ __align__(16) __bf16 Wt[128 * 32];   //  8,192 B
    __shared__ __align__(16) __bf16 A2[128 * 136];  // 34,816 B; Mf (f32 64x132) aliases
    __shared__ float s_r2[128], s_ea[128], s_sg[128], s_g[128];
    __shared__ float s_diff[128 * 3];
    __shared__ int s_dst[128], s_src[128];

    float* Mf = (float*)A2;

    const int t = threadIdx.x;
    const int e0 = blockIdx.x * 128;
    const int w = t >> 6;
    const int lane = t & 63;
    const int m_ = lane & 15;
    const int q = lane >> 4;

    // per-edge scalars: 3 coalesced loads, precomputed in sorted order
    if (t < 128) {
        float4 g = e_geo[e0 + t];
        int2 nd = e_nodes[e0 + t];
        float2 gt = e_gate[e0 + t];
        s_diff[t * 3 + 0] = g.x; s_diff[t * 3 + 1] = g.y; s_diff[t * 3 + 2] = g.z;
        s_r2[t] = g.w;
        s_ea[t] = gt.x;
        s_sg[t] = gt.y;
        s_src[t] = nd.x;
        s_dst[t] = nd.y;
    }
    __syncthreads();

    const int el0 = w * 16 + m_;
    const int el1 = 64 + w * 16 + m_;
    const int nd0 = s_dst[el0], ns0 = s_src[el0];
    const int nd1 = s_dst[el1], ns1 = s_src[el1];

    f32x4_t acc[2][8];
#pragma unroll
    for (int et = 0; et < 2; ++et)
#pragma unroll
        for (int ot = 0; ot < 8; ++ot) acc[et][ot] = (f32x4_t){0.f, 0.f, 0.f, 0.f};

    const int wrow = t >> 2;
    const int wpart = (t & 3) * 8;

    // ---- layer 1: K = 256 (cols 0..127 = x[dst], 128..255 = x[src]), xf prefetch ----
    bf16x8_t xf0 = *(const bf16x8_t*)(xb + (long)nd0 * 128 + q * 8);
    bf16x8_t xf1 = *(const bf16x8_t*)(xb + (long)nd1 * 128 + q * 8);
#pragma unroll
    for (int ks = 0; ks < 8; ++ks) {
        uint4 v0 = *(const uint4*)(We1T + wrow * 256 + ks * 32 + wpart);
        uint4 v1 = *(const uint4*)(We1T + (wrow + 64) * 256 + ks * 32 + wpart);
        bf16x8_t nxf0, nxf1;
        if (ks < 7) {
            int col = ((ks + 1) & 3) * 32 + q * 8;
            nxf0 = *(const bf16x8_t*)(xb + (long)(ks + 1 < 4 ? nd0 : ns0) * 128 + col);
            nxf1 = *(const bf16x8_t*)(xb + (long)(ks + 1 < 4 ? nd1 : ns1) * 128 + col);
        }
        __syncthreads();
        *(uint4*)(Wt + wrow * 32 + wpart) = v0;
        *(uint4*)(Wt + (wrow + 64) * 32 + wpart) = v1;
        __syncthreads();
#pragma unroll
        for (int ot = 0; ot < 8; ++ot) {
            bf16x8_t wf = *(const bf16x8_t*)(Wt + (ot * 16 + m_) * 32 + q * 8);
            acc[0][ot] = __builtin_amdgcn_mfma_f32_16x16x32_bf16(wf, xf0, acc[0][ot], 0, 0, 0);
            acc[1][ot] = __builtin_amdgcn_mfma_f32_16x16x32_bf16(wf, xf1, acc[1][ot], 0, 0, 0);
        }
        if (ks < 7) { xf0 = nxf0; xf1 = nxf1; }
    }

    // epilogue 1: + b + r2*W[256] + ea*W[257], SiLU -> A2 (bf16, packed writes)
#pragma unroll
    for (int et = 0; et < 2; ++et) {
        int e = et ? el1 : el0;
        float r2 = s_r2[e], ea = s_ea[e];
#pragma unroll
        for (int ot = 0; ot < 8; ++ot) {
            int oc = ot * 16 + q * 4;
            float4 b1 = *(const float4*)(be1 + oc);
            float4 w6 = *(const float4*)(We1 + 256 * 128 + oc);
            float4 w7 = *(const float4*)(We1 + 257 * 128 + oc);
            union { __bf16 h[4]; uint2 u2; } pk;
            pk.h[0] = (__bf16)silu_f(acc[et][ot][0] + b1.x + r2 * w6.x + ea * w7.x);
            pk.h[1] = (__bf16)silu_f(acc[et][ot][1] + b1.y + r2 * w6.y + ea * w7.y);
            pk.h[2] = (__bf16)silu_f(acc[et][ot][2] + b1.z + r2 * w6.z + ea * w7.z);
            pk.h[3] = (__bf16)silu_f(acc[et][ot][3] + b1.w + r2 * w6.w + ea * w7.w);
            *(uint2*)(A2 + e * 136 + oc) = pk.u2;
        }
    }

#pragma unroll
    for (int et = 0; et < 2; ++et)
#pragma unroll
        for (int ot = 0; ot < 8; ++ot) acc[et][ot] = (f32x4_t){0.f, 0.f, 0.f, 0.f};

    // ---- layer 2: K = 128, B-operand = A2 rows (same-wave LDS) ----
    for (int ks = 0; ks < 4; ++ks) {
        uint4 v0 = *(const uint4*)(We2T + wrow * 128 + ks * 32 + wpart);
        uint4 v1 = *(const uint4*)(We2T + (wrow + 64) * 128 + ks * 32 + wpart);
        __syncthreads();
        *(uint4*)(Wt + wrow * 32 + wpart) = v0;
        *(uint4*)(Wt + (wrow + 64) * 32 + wpart) = v1;
        __syncthreads();
        bf16x8_t af0 = *(const bf16x8_t*)(A2 + el0 * 136 + ks * 32 + q * 8);
        bf16x8_t af1 = *(const bf16x8_t*)(A2 + el1 * 136 + ks * 32 + q * 8);
#pragma unroll
        for (int ot = 0; ot < 8; ++ot) {
            bf16x8_t wf = *(const bf16x8_t*)(Wt + (ot * 16 + m_) * 32 + q * 8);
            acc[0][ot] = __builtin_amdgcn_mfma_f32_16x16x32_bf16(wf, af0, acc[0][ot], 0, 0, 0);
            acc[1][ot] = __builtin_amdgcn_mfma_f32_16x16x32_bf16(wf, af1, acc[1][ot], 0, 0, 0);
        }
    }

    // epilogue 2: + b, SiLU, * s[src]; gamma via q-lane shuffle reduce
    {
        float sg0 = s_sg[el0], sg1 = s_sg[el1];
        float gp0 = 0.f, gp1 = 0.f;
#pragma unroll
        for (int ot = 0; ot < 8; ++ot) {
            int oc = ot * 16 + q * 4;
            float4 b2 = *(const float4*)(be2 + oc);
            float4 wc = *(const float4*)(Wc + oc);
            f32x4_t v0 = acc[0][ot], v1 = acc[1][ot];
            v0[0] = silu_f(v0[0] + b2.x) * sg0; v0[1] = silu_f(v0[1] + b2.y) * sg0;
            v0[2] = silu_f(v0[2] + b2.z) * sg0; v0[3] = silu_f(v0[3] + b2.w) * sg0;
            v1[0] = silu_f(v1[0] + b2.x) * sg1; v1[1] = silu_f(v1[1] + b2.y) * sg1;
            v1[2] = silu_f(v1[2] + b2.z) * sg1; v1[3] = silu_f(v1[3] + b2.w) * sg1;
            acc[0][ot] = v0; acc[1][ot] = v1;
            gp0 += v0[0] * wc.x + v0[1] * wc.y + v0[2] * wc.z + v0[3] * wc.w;
            gp1 += v1[0] * wc.x + v1[1] * wc.y + v1[2] * wc.z + v1[3] * wc.w;
        }
        gp0 += __shfl_xor(gp0, 16); gp0 += __shfl_xor(gp0, 32);
        gp1 += __shfl_xor(gp1, 16); gp1 += __shfl_xor(gp1, 32);
        if (q == 0) {
            float b0 = bc[0];
            s_g[el0] = gp0 + b0;
            s_g[el1] = gp1 + b0;
        }
    }
    __syncthreads();   // P0: all A2 reads done (Mf aliases), s_g visible

    // coord: 24 threads, 3 axes x 8 row-chunks of 16 (atomics make chunk splits safe)
    if (t < 24) {
        int ax = t % 3, ch = t / 3;
        int base = ch * 16;
        float run = 0.f;
        int cur = s_dst[base];
        for (int r = 0; r < 16; ++r) {
            int rr = base + r;
            int d = s_dst[rr];
            if (d != cur) {
                atomicAdd(&coordsum[cur * 3 + ax], run);
                run = 0.f; cur = d;
            }
            run += s_g[rr] * s_diff[rr * 3 + ax];
        }
        atomicAdd(&coordsum[cur * 3 + ax], run);
    }

    // msum: two phases of 64 edges; all 256 threads (col x row-half), serial length 32
#pragma unroll
    for (int ph = 0; ph < 2; ++ph) {
        int lr = w * 16 + m_;
#pragma unroll
        for (int ot = 0; ot < 8; ++ot)
            *(f32x4_t*)(Mf + lr * 132 + ot * 16 + q * 4) = acc[ph][ot];
        __syncthreads();   // Mf complete
        {
            int c = t & 127;
            int half = t >> 7;               // wave-uniform (waves 0,1 -> 0; 2,3 -> 1)
            int base = ph * 64 + half * 32;
            float run = 0.f;
            int cur = s_dst[base];
            for (int r = 0; r < 32; ++r) {
                int d = s_dst[base + r];     // wave-uniform branch
                if (d != cur) {
                    atomicAdd(&msum[(long)cur * 128 + c], run);
                    run = 0.f; cur = d;
                }
                run += Mf[(half * 32 + r) * 132 + c];
            }
            atomicAdd(&msum[(long)cur * 128 + c], run);
        }
        __syncthreads();   // reduce done before Mf overwrite / exit
    }
}

// ---------------- node kernel: normalize agg + 2-layer node MLP + pos update ----------------
__global__ __launch_bounds__(256, 2)
void node_kernel(const __bf16* __restrict__ xb,
                 const float* __restrict__ msum,
                 const int* __restrict__ off,
                 const __bf16* __restrict__ Wn1T,
                 const float* __restrict__ bn1,
                 const __bf16* __restrict__ Wn2T,
                 const float* __restrict__ bn2,
                 const float* __restrict__ pos,
                 const float* __restrict__ csum,
                 float* __restrict__ xout,
                 float* __restrict__ pout) {
    __shared__ __align__(16) __bf16 Abf[64 * 264];
    __shared__ __align__(16) __bf16 Wt[128 * 56];
    __shared__ __align__(16) __bf16 A2[64 * 136];

    const int t = threadIdx.x;
    const int r0 = blockIdx.x * 64;
    const int w = t >> 6;
    const int lane = t & 63;
    const int m_ = lane & 15;
    const int q = lane >> 4;

    // pos update for this block's 64 nodes (independent of the MLP)
    if (t < 192) {
        int node = r0 + t / 3;
        if (node < NN) {
            int dg = off[node + 1] - off[node];
            float inv = 1.f / (float)(dg < 1 ? 1 : dg);
            int fl = node * 3 + t % 3;
            pout[fl] = pos[fl] + csum[fl] * inv;
        }
    }

    for (int i = 0; i < 8; ++i) {
        int id = t + 256 * i;
        int rl = id >> 5, ch = id & 31;
        int row = r0 + rl;
        int c8 = (ch & 15) * 8;
        union { __bf16 h[8]; uint4 u; } pk;
        if (row < NN) {
            if (ch < 16) {
                pk.u = *(const uint4*)(xb + (long)row * 128 + c8);
            } else {
                const float* mp = msum + (long)row * 128 + c8;
                int dg = off[row + 1] - off[row];
                float inv = 1.f / (float)(dg < 1 ? 1 : dg);
#pragma unroll
                for (int j = 0; j < 8; ++j) pk.h[j] = (__bf16)(mp[j] * inv);
            }
        } else {
            pk.u = make_uint4(0, 0, 0, 0);
        }
        *(uint4*)(Abf + rl * 264 + ((ch < 16) ? 0 : 128) + c8) = pk.u;
    }
    __syncthreads();

    f32x4_t acc[8];
#pragma unroll
    for (int ct = 0; ct < 8; ++ct) acc[ct] = (f32x4_t){0.f, 0.f, 0.f, 0.f};

    for (int ks = 0; ks < 8; ++ks) {
#pragma unroll
        for (int i = 0; i < 2; ++i) {
            int c = t + 256 * i;
            int n = c >> 2, ko = (c & 3) * 8;
            uint4 v = *(const uint4*)(Wn1T + n * 256 + ks * 32 + ko);
            *(uint4*)(Wt + n * 56 + ko) = v;
        }
        __syncthreads();
        bf16x8_t a = *(const bf16x8_t*)(Abf + (w * 16 + m_) * 264 + ks * 32 + q * 8);
#pragma unroll
        for (int ct = 0; ct < 8; ++ct) {
            bf16x8_t b = *(const bf16x8_t*)(Wt + (ct * 16 + m_) * 56 + q * 8);
            acc[ct] = __builtin_amdgcn_mfma_f32_16x16x32_bf16(a, b, acc[ct], 0, 0, 0);
        }
        __syncthreads();
    }
#pragma unroll
    for (int ct = 0; ct < 8; ++ct) {
        int c = ct * 16 + m_;
        float b1 = bn1[c];
#pragma unroll
        for (int r = 0; r < 4; ++r) {
            int el = w * 16 + q * 4 + r;
            float v = acc[ct][r] + b1;
            A2[el * 136 + c] = (__bf16)silu_f(v);
        }
    }
    __syncthreads();

#pragma unroll
    for (int ct = 0; ct < 8; ++ct) acc[ct] = (f32x4_t){0.f, 0.f, 0.f, 0.f};

    for (int ks = 0; ks < 4; ++ks) {
#pragma unroll
        for (int i = 0; i < 2; ++i) {
            int c = t + 256 * i;
            int n = c >> 2, ko = (c & 3) * 8;
            uint4 v = *(const uint4*)(Wn2T + n * 128 + ks * 32 + ko);
            *(uint4*)(Wt + n * 56 + ko) = v;
        }
        __syncthreads();
        bf16x8_t a = *(const bf16x8_t*)(A2 + (w * 16 + m_) * 136 + ks * 32 + q * 8);
#pragma unroll
        for (int ct = 0; ct < 8; ++ct) {
            bf16x8_t b = *(const bf16x8_t*)(Wt + (ct * 16 + m_) * 56 + q * 8);
            acc[ct] = __builtin_amdgcn_mfma_f32_16x16x32_bf16(a, b, acc[ct], 0, 0, 0);
        }
        __syncthreads();
    }
#pragma unroll
    for (int ct = 0; ct < 8; ++ct) {
        int c = ct * 16 + m_;
        float b2 = bn2[c];
#pragma unroll
        for (int r = 0; r < 4; ++r) {
            int el = w * 16 + q * 4 + r;
            int row = r0 + el;
            if (row < NN) xout[(long)row * 128 + c] = acc[ct][r] + b2;
        }
    }
}

extern "C" void kernel_launch(void* const* d_in, const int* in_sizes, int n_in,
                              void* d_out, int out_size, void* d_ws, size_t ws_size,
                              hipStream_t stream) {
    const float* x     = (const float*)d_in[0];
    const float* pos   = (const float*)d_in[1];
    const int*   eidx  = (const int*)d_in[2];
    const float* eattr = (const float*)d_in[3];
    const float* s     = (const float*)d_in[4];
    const float* We1   = (const float*)d_in[5];
    const float* be1   = (const float*)d_in[6];
    const float* We2   = (const float*)d_in[7];
    const float* be2   = (const float*)d_in[8];
    const float* Wn1   = (const float*)d_in[9];
    const float* bn1   = (const float*)d_in[10];
    const float* Wn2   = (const float*)d_in[11];
    const float* bn2   = (const float*)d_in[12];
    const float* Wc    = (const float*)d_in[13];
    const float* bc    = (const float*)d_in[14];

    char* ws = (char*)d_ws;
    __bf16* xb     = (__bf16*)(ws);                 // 12,800,000
    __bf16* We1T   = (__bf16*)(ws + 12800000);      //     65,536
    __bf16* We2T   = (__bf16*)(ws + 12865536);      //     32,768
    __bf16* Wn1T   = (__bf16*)(ws + 12898304);      //     65,536
    __bf16* Wn2T   = (__bf16*)(ws + 12963840);      //     32,768
    float*  msum   = (float*)(ws + 12996608);       // 25,600,000
    float*  csum   = (float*)(ws + 38596608);       //    600,000
    int*    hist   = (int*)(ws + 39196608);         //    200,000
    int*    off    = (int*)(ws + 39396608);         //    200,064
    int*    cursor = (int*)(ws + 39596672);         //    200,064
    float4* e_geo  = (float4*)(ws + 39796736);      // 12,800,000 (16B aligned)
    int2*   e_nodes= (int2*)(ws + 52596736);        //  6,400,000
    float2* e_gate = (float2*)(ws + 58996736);      //  6,400,000
    int*    bsum   = (int*)(ws + 65396736);         //      1,024 (end 65,397,760)

    float* xout = (float*)d_out;
    float* pout = xout + (size_t)NN * 128;

    // zero msum + csum + hist (contiguous, 26.4 MB)
    hipMemsetAsync(ws + 12996608, 0, 26400000, stream);
    prep_kernel<<<1024, 256, 0, stream>>>(x, We1, We2, Wn1, Wn2, eidx,
                                          xb, We1T, We2T, Wn1T, Wn2T, hist);
    scan_a<<<SCAN_BLOCKS, 256, 0, stream>>>(hist, bsum);
    scan_b<<<1, 256, 0, stream>>>(bsum);
    scan_c<<<SCAN_BLOCKS, 256, 0, stream>>>(hist, bsum, off, cursor);
    scatter_kernel<<<(EE + 255) / 256, 256, 0, stream>>>(eidx, pos, eattr, s, cursor,
                                                         e_geo, e_nodes, e_gate);
    edge_kernel<<<EE / 128, 256, 0, stream>>>(xb, e_geo, e_nodes, e_gate,
                                              We1T, We1, be1, We2T, be2, Wc, bc,
                                              msum, csum);
    node_kernel<<<(NN + 63) / 64, 256, 0, stream>>>(xb, msum, off, Wn1T, bn1, Wn2T, bn2,
                                                    pos, csum, xout, pout);
}